// Round 2
// baseline (177.309 us; speedup 1.0000x reference)
//
#include <hip/hip_runtime.h>
#include <math.h>

#define TPB 128   // 2 waves per block; both waves share one 64x64 tile, split on K

// Coords pre-scaled by log2(e): exp2(|dt'-dp'|) == e^{|dt-dp|}; cutoff test
// runs on squared scaled distances (no sqrt->cmp dependency).
#define L2E 1.4426950408889634f

// sum_k sigmoid(a_k - d) = num(e)/den(e), e = exp(d), a_k = .5,1,2,4.
// Coefficients: elementary symmetric functions of C_k = e^{-a_k}.
#define A1c 1.1280610230094226f
#define A2c 0.3753279228541867f
#define A3c 0.0366994760193147f
#define A4c 0.0005530843701478f
#define B1c 3.3841830690282678f   // 3*A1
#define B2c 0.7506558457083734f   // 2*A2
#define B3c 0.0366994760193147f   // A3
// Self-pair (d=0, e=1): eps = sig(.5)+sig(1)+sig(2)+sig(4) = 3.2163290...
#define EPS_SELF 3.2163290f

typedef float f2 __attribute__((ext_vector_type(2)));

static __device__ __forceinline__ f2 f2fma(f2 a, f2 b, f2 c) {
  return __builtin_elementwise_fma(a, b, c);
}
static __device__ __forceinline__ f2 splat(float x) {
  f2 r; r.x = x; r.y = x; return r;
}

__global__ __launch_bounds__(TPB, 6) void lddt_fused(
    const float* __restrict__ pred, const float* __restrict__ truec,
    const int* __restrict__ isdna, const int* __restrict__ isrna,
    float2* __restrict__ part, unsigned int* __restrict__ ticket,
    float* __restrict__ out, int N, int C)
{
  const int wv   = threadIdx.x >> 6;   // which K-half of the tile (0/1)
  const int lane = threadIdx.x & 63;
  const int t = blockIdx.x;            // linear upper-triangle tile id
  const int b = blockIdx.y;
  const int T = gridDim.x;             // tiles per batch
  const int B = gridDim.y;

  // tile id -> (ic, jc), jc >= ic (wave-uniform scalar math)
  const float fC = (float)C;
  int ic = (int)((2.0f*fC + 1.0f -
                  sqrtf((2.0f*fC + 1.0f)*(2.0f*fC + 1.0f) - 8.0f*(float)t)) * 0.5f);
  if (ic > C - 1) ic = C - 1;
  if (ic < 0) ic = 0;
  while (ic > 0 && t < ic*C - ((ic*(ic-1)) >> 1)) --ic;
  while (t >= (ic+1)*C - (((ic+1)*ic) >> 1)) ++ic;
  const int jc = ic + t - (ic*C - ((ic*(ic-1)) >> 1));
  const bool diag = (ic == jc);

  const float C30SQ = (30.0f*L2E)*(30.0f*L2E);
  const float C15SQ = (15.0f*L2E)*(15.0f*L2E);

  // SoA j-tile staging: f2 element k packs j = 2k, 2k+1 (wave-uniform
  // broadcast ds_read_b64 in the loop -> conflict-free).
  __shared__ f2 spx[32], spy[32], spz[32];
  __shared__ f2 stx[32], sty[32], stz[32];
  __shared__ f2 scut[32];
  __shared__ float2 blkred[2];
  __shared__ unsigned int sticket;

  {
    const int j = jc * 64 + lane;
    const size_t jb = (size_t)b * N + j;
    if (wv == 0) {       // wave 0 stages pred coords + cutoff class
      const float* pp = pred + jb * 3;
      ((float*)spx)[lane] = pp[0]*L2E;
      ((float*)spy)[lane] = pp[1]*L2E;
      ((float*)spz)[lane] = pp[2]*L2E;
      ((float*)scut)[lane] = ((isdna[jb] | isrna[jb]) != 0) ? C30SQ : C15SQ;
    } else {             // wave 1 stages true coords
      const float* tt = truec + jb * 3;
      ((float*)stx)[lane] = tt[0]*L2E;
      ((float*)sty)[lane] = tt[1]*L2E;
      ((float*)stz)[lane] = tt[2]*L2E;
    }
  }

  const int i = ic * 64 + lane;
  const size_t ib = (size_t)b * N + i;
  const f2 pix2 = splat(pred[ib*3+0]*L2E);
  const f2 piy2 = splat(pred[ib*3+1]*L2E);
  const f2 piz2 = splat(pred[ib*3+2]*L2E);
  const f2 tix2 = splat(truec[ib*3+0]*L2E);
  const f2 tiy2 = splat(truec[ib*3+1]*L2E);
  const f2 tiz2 = splat(truec[ib*3+2]*L2E);
  // cutoff = (nuc_i && nuc_j) ? 30 : 15  ==  min(cut_i, cut_j)
  const f2 cuti2 = splat(((isdna[ib] | isrna[ib]) != 0) ? C30SQ : C15SQ);

  const f2 vA4 = splat(A4c), vA3 = splat(A3c), vA2 = splat(A2c), vA1 = splat(A1c);
  const f2 vB3 = splat(B3c), vB2 = splat(B2c), vB1 = splat(B1c);
  const f2 v1 = splat(1.0f), v4 = splat(4.0f);

  __syncthreads();

  f2  sum2 = splat(0.0f);
  int cnt = 0;

  // Branch-free packed loop over this wave's K-half; diag tiles include the
  // self-pair (d=0 -> e=1, eps=EPS_SELF, inc=true exactly) subtracted
  // analytically after the loop.
  const int k0 = wv * 16;
#pragma unroll 4
  for (int k = k0; k < k0 + 16; ++k) {
    f2 dx = spx[k] - pix2;
    f2 dy = spy[k] - piy2;
    f2 dz = spz[k] - piz2;
    f2 d2p = f2fma(dx, dx, f2fma(dy, dy, dz * dz));
    f2 ex = stx[k] - tix2;
    f2 ey = sty[k] - tiy2;
    f2 ez = stz[k] - tiz2;
    f2 d2t = f2fma(ex, ex, f2fma(ey, ey, ez * ez));

    f2 dpv, dtv;
    dpv.x = __builtin_amdgcn_sqrtf(d2p.x);
    dpv.y = __builtin_amdgcn_sqrtf(d2p.y);
    dtv.x = __builtin_amdgcn_sqrtf(d2t.x);
    dtv.y = __builtin_amdgcn_sqrtf(d2t.y);
    f2 diff = dtv - dpv;

    f2 e;
    e.x = __builtin_amdgcn_exp2f(fabsf(diff.x));
    e.y = __builtin_amdgcn_exp2f(fabsf(diff.y));

    f2 den = f2fma(f2fma(f2fma(f2fma(vA4, e, vA3), e, vA2), e, vA1), e, v1);
    f2 num = f2fma(f2fma(f2fma(vB3, e, vB2), e, vB1), e, v4);
    f2 r;
    r.x = __builtin_amdgcn_rcpf(den.x);
    r.y = __builtin_amdgcn_rcpf(den.y);
    f2 eps = num * r;

    f2 cut = __builtin_elementwise_min(cuti2, scut[k]);
    bool i0 = d2t.x < cut.x;
    bool i1 = d2t.y < cut.y;
    cnt += (int)__popcll(__ballot(i0));
    cnt += (int)__popcll(__ballot(i1));
    f2 add;
    add.x = i0 ? eps.x : 0.0f;
    add.y = i1 ? eps.y : 0.0f;
    sum2 += add;
  }

  float sum = sum2.x + sum2.y;
  // Self-pairs of a diag tile: lane L's self is at k = L>>1, which lives in
  // wave (L>>5)'s K-half; each wave's ballots counted 32 of them.
  if (diag) {
    if ((lane >> 5) == wv) sum -= EPS_SELF;
    cnt -= 32;
  }

  // wave64 butterfly reduce on sum (cnt already wave-uniform via ballot)
  for (int off = 32; off > 0; off >>= 1)
    sum += __shfl_down(sum, off, 64);

  if (lane == 0) {
    const float w = diag ? 1.0f : 2.0f;
    blkred[wv] = make_float2(0.25f * w * sum, w * (float)cnt);
  }
  __syncthreads();

  // ---- last-block-done finalization (replaces the second kernel) ----
  if (threadIdx.x == 0) {
    const float2 a = blkred[0], c = blkred[1];
    union { float2 f; unsigned long long u; } pk;
    pk.f = make_float2(a.x + c.x, a.y + c.y);
    // agent-scope release store: visible across XCD L2s to whoever
    // acquires the ticket counter after us (Guideline 16).
    __hip_atomic_store((unsigned long long*)&part[(size_t)b * T + t], pk.u,
                       __ATOMIC_RELEASE, __HIP_MEMORY_SCOPE_AGENT);
    sticket = __hip_atomic_fetch_add(ticket, 1u, __ATOMIC_ACQ_REL,
                                     __HIP_MEMORY_SCOPE_AGENT);
  }
  __syncthreads();
  if (sticket != (unsigned int)(T * B) - 1u) return;

  // Last block: reduce all B*T partials (33 KB) and write the scalar out.
  __shared__ float rs[2], rc[2];
  float acc = 0.0f;
  for (int bb = 0; bb < B; ++bb) {
    float s = 0.0f, cc = 0.0f;
    for (int k = threadIdx.x; k < T; k += TPB) {
      union { float2 f; unsigned long long u; } pk;
      pk.u = __hip_atomic_load((const unsigned long long*)&part[(size_t)bb * T + k],
                               __ATOMIC_RELAXED, __HIP_MEMORY_SCOPE_AGENT);
      s += pk.f.x;
      cc += pk.f.y;
    }
    for (int off = 32; off > 0; off >>= 1) {
      s += __shfl_down(s, off, 64);
      cc += __shfl_down(cc, off, 64);
    }
    if (lane == 0) { rs[wv] = s; rc[wv] = cc; }
    __syncthreads();
    if (threadIdx.x == 0) acc += (rs[0] + rs[1]) / fmaxf(rc[0] + rc[1], 1.0f);
    __syncthreads();
  }
  if (threadIdx.x == 0) out[0] = 1.0f - acc / (float)B;
}

extern "C" void kernel_launch(void* const* d_in, const int* in_sizes, int n_in,
                              void* d_out, int out_size, void* d_ws, size_t ws_size,
                              hipStream_t stream)
{
  const float* pred  = (const float*)d_in[0];
  const float* truec = (const float*)d_in[1];
  const int*   isdna = (const int*)d_in[2];
  const int*   isrna = (const int*)d_in[3];
  float* out = (float*)d_out;

  // ws layout: [0,4) ticket counter (zeroed each launch); [256, ...) partials
  unsigned int* ticket = (unsigned int*)d_ws;
  float2* part = (float2*)((char*)d_ws + 256);

  const int B = 2;
  const int N = in_sizes[2] / B;       // 4096
  const int C = N / 64;                // 64 chunks
  const int T = C * (C + 1) / 2;       // 2080 triangle tiles

  hipMemsetAsync(d_ws, 0, 4, stream);  // graph-capturable memset node

  dim3 grid(T, B);                     // 1 tile per block, K split across 2 waves
  lddt_fused<<<grid, TPB, 0, stream>>>(pred, truec, isdna, isrna,
                                       part, ticket, out, N, C);
}

// Round 3
// 132.551 us; speedup vs baseline: 1.3377x; 1.3377x over previous
//
#include <hip/hip_runtime.h>
#include <math.h>

#define TPB 128   // 2 waves per block; both waves share one 64x64 tile, split on K

// Coords pre-scaled by log2(e): exp2(|dt'-dp'|) == e^{|dt-dp|}; cutoff test
// runs on squared scaled distances (no sqrt->cmp dependency).
#define L2E 1.4426950408889634f

// sum_k sigmoid(a_k - d) = num(e)/den(e), e = exp(d), a_k = .5,1,2,4.
// Coefficients: elementary symmetric functions of C_k = e^{-a_k}.
#define A1c 1.1280610230094226f
#define A2c 0.3753279228541867f
#define A3c 0.0366994760193147f
#define A4c 0.0005530843701478f
#define B1c 3.3841830690282678f   // 3*A1
#define B2c 0.7506558457083734f   // 2*A2
#define B3c 0.0366994760193147f   // A3
// Self-pair (d=0, e=1): eps = sig(.5)+sig(1)+sig(2)+sig(4) = 3.2163290...
#define EPS_SELF 3.2163290f

typedef float f2 __attribute__((ext_vector_type(2)));

static __device__ __forceinline__ f2 f2fma(f2 a, f2 b, f2 c) {
  return __builtin_elementwise_fma(a, b, c);
}
static __device__ __forceinline__ f2 splat(float x) {
  f2 r; r.x = x; r.y = x; return r;
}

// Completion tickets live in __device__ globals: zero-initialized at module
// load, NEVER reset, NOT in the harness-poisoned workspace. Last-of-iteration
// is detected modulo the per-iteration increment count (4160 = 64 leaves x 65),
// so graph replays / rocprof replays stay consistent without any memset node.
__device__ unsigned int g_leaf[64 * 32];   // one counter per 128B line
__device__ unsigned int g_root;

__global__ __launch_bounds__(TPB, 6) void lddt_fused(
    const float* __restrict__ pred, const float* __restrict__ truec,
    const int* __restrict__ isdna, const int* __restrict__ isrna,
    float2* __restrict__ part, float* __restrict__ out, int N, int C)
{
  const int wv   = threadIdx.x >> 6;   // which K-half of the tile (0/1)
  const int lane = threadIdx.x & 63;
  const int t = blockIdx.x;            // linear upper-triangle tile id
  const int b = blockIdx.y;
  const int T = gridDim.x;             // tiles per batch (2080)
  const int B = gridDim.y;             // batches (2)

  // tile id -> (ic, jc), jc >= ic (wave-uniform scalar math)
  const float fC = (float)C;
  int ic = (int)((2.0f*fC + 1.0f -
                  sqrtf((2.0f*fC + 1.0f)*(2.0f*fC + 1.0f) - 8.0f*(float)t)) * 0.5f);
  if (ic > C - 1) ic = C - 1;
  if (ic < 0) ic = 0;
  while (ic > 0 && t < ic*C - ((ic*(ic-1)) >> 1)) --ic;
  while (t >= (ic+1)*C - (((ic+1)*ic) >> 1)) ++ic;
  const int jc = ic + t - (ic*C - ((ic*(ic-1)) >> 1));
  const bool diag = (ic == jc);

  const float C30SQ = (30.0f*L2E)*(30.0f*L2E);
  const float C15SQ = (15.0f*L2E)*(15.0f*L2E);

  // SoA j-tile staging: f2 element k packs j = 2k, 2k+1 (wave-uniform
  // broadcast ds_read_b64 in the loop -> conflict-free).
  __shared__ f2 spx[32], spy[32], spz[32];
  __shared__ f2 stx[32], sty[32], stz[32];
  __shared__ f2 scut[32];
  __shared__ float2 blkred[2];
  __shared__ int slast;

  {
    const int j = jc * 64 + lane;
    const size_t jb = (size_t)b * N + j;
    if (wv == 0) {       // wave 0 stages pred coords + cutoff class
      const float* pp = pred + jb * 3;
      ((float*)spx)[lane] = pp[0]*L2E;
      ((float*)spy)[lane] = pp[1]*L2E;
      ((float*)spz)[lane] = pp[2]*L2E;
      ((float*)scut)[lane] = ((isdna[jb] | isrna[jb]) != 0) ? C30SQ : C15SQ;
    } else {             // wave 1 stages true coords
      const float* tt = truec + jb * 3;
      ((float*)stx)[lane] = tt[0]*L2E;
      ((float*)sty)[lane] = tt[1]*L2E;
      ((float*)stz)[lane] = tt[2]*L2E;
    }
  }

  const int i = ic * 64 + lane;
  const size_t ib = (size_t)b * N + i;
  const f2 pix2 = splat(pred[ib*3+0]*L2E);
  const f2 piy2 = splat(pred[ib*3+1]*L2E);
  const f2 piz2 = splat(pred[ib*3+2]*L2E);
  const f2 tix2 = splat(truec[ib*3+0]*L2E);
  const f2 tiy2 = splat(truec[ib*3+1]*L2E);
  const f2 tiz2 = splat(truec[ib*3+2]*L2E);
  // cutoff = (nuc_i && nuc_j) ? 30 : 15  ==  min(cut_i, cut_j)
  const f2 cuti2 = splat(((isdna[ib] | isrna[ib]) != 0) ? C30SQ : C15SQ);

  const f2 vA4 = splat(A4c), vA3 = splat(A3c), vA2 = splat(A2c), vA1 = splat(A1c);
  const f2 vB3 = splat(B3c), vB2 = splat(B2c), vB1 = splat(B1c);
  const f2 v1 = splat(1.0f), v4 = splat(4.0f);

  __syncthreads();

  f2  sum2 = splat(0.0f);
  int cnt = 0;

  // Branch-free packed loop over this wave's K-half; diag tiles include the
  // self-pair (d=0 -> e=1, eps=EPS_SELF, inc=true exactly) subtracted
  // analytically after the loop.
  const int k0 = wv * 16;
#pragma unroll 4
  for (int k = k0; k < k0 + 16; ++k) {
    f2 dx = spx[k] - pix2;
    f2 dy = spy[k] - piy2;
    f2 dz = spz[k] - piz2;
    f2 d2p = f2fma(dx, dx, f2fma(dy, dy, dz * dz));
    f2 ex = stx[k] - tix2;
    f2 ey = sty[k] - tiy2;
    f2 ez = stz[k] - tiz2;
    f2 d2t = f2fma(ex, ex, f2fma(ey, ey, ez * ez));

    f2 dpv, dtv;
    dpv.x = __builtin_amdgcn_sqrtf(d2p.x);
    dpv.y = __builtin_amdgcn_sqrtf(d2p.y);
    dtv.x = __builtin_amdgcn_sqrtf(d2t.x);
    dtv.y = __builtin_amdgcn_sqrtf(d2t.y);
    f2 diff = dtv - dpv;

    f2 e;
    e.x = __builtin_amdgcn_exp2f(fabsf(diff.x));
    e.y = __builtin_amdgcn_exp2f(fabsf(diff.y));

    f2 den = f2fma(f2fma(f2fma(f2fma(vA4, e, vA3), e, vA2), e, vA1), e, v1);
    f2 num = f2fma(f2fma(f2fma(vB3, e, vB2), e, vB1), e, v4);
    f2 r;
    r.x = __builtin_amdgcn_rcpf(den.x);
    r.y = __builtin_amdgcn_rcpf(den.y);
    f2 eps = num * r;

    f2 cut = __builtin_elementwise_min(cuti2, scut[k]);
    bool i0 = d2t.x < cut.x;
    bool i1 = d2t.y < cut.y;
    cnt += (int)__popcll(__ballot(i0));
    cnt += (int)__popcll(__ballot(i1));
    f2 add;
    add.x = i0 ? eps.x : 0.0f;
    add.y = i1 ? eps.y : 0.0f;
    sum2 += add;
  }

  float sum = sum2.x + sum2.y;
  // Self-pairs of a diag tile: lane L's self is at k = L>>1, which lives in
  // wave (L>>5)'s K-half; each wave's ballots counted 32 of them.
  if (diag) {
    if ((lane >> 5) == wv) sum -= EPS_SELF;
    cnt -= 32;
  }

  // wave64 butterfly reduce on sum (cnt already wave-uniform via ballot)
  for (int off = 32; off > 0; off >>= 1)
    sum += __shfl_down(sum, off, 64);

  if (lane == 0) {
    const float w = diag ? 1.0f : 2.0f;
    blkred[wv] = make_float2(0.25f * w * sum, w * (float)cnt);
  }
  __syncthreads();

  // ---- hierarchical last-block-done finalization ----
  // Hot path per block: one sc1 release store (8B) + one RELEASE fetch_add on
  // one of 64 spread leaf counters (no acquire -> no per-block cache inv).
  // 64 leaf-last blocks touch the root; the single root-last block reduces.
  if (threadIdx.x == 0) {
    const float2 a = blkred[0], c = blkred[1];
    union { float2 f; unsigned long long u; } pk;
    pk.f = make_float2(a.x + c.x, a.y + c.y);
    const int jid = b * T + t;                  // 0 .. 4159
    __hip_atomic_store((unsigned long long*)&part[jid], pk.u,
                       __ATOMIC_RELEASE, __HIP_MEMORY_SCOPE_AGENT);
    const unsigned int l =
        __hip_atomic_fetch_add(&g_leaf[(jid & 63) * 32], 1u,
                               __ATOMIC_RELEASE, __HIP_MEMORY_SCOPE_AGENT);
    int last = 0;
    if ((l + 1u) % 65u == 0u) {                 // last of this leaf (65/iter)
      const unsigned int r =
          __hip_atomic_fetch_add(&g_root, 1u,
                                 __ATOMIC_ACQ_REL, __HIP_MEMORY_SCOPE_AGENT);
      last = (((r + 1u) & 63u) == 0u);          // last of 64 leaves
    }
    slast = last;
  }
  __syncthreads();
  if (!slast) return;

  // Root-last block: all 4160 partials are at the coherent point (release
  // chain); invalidate local caches, then reduce 33 KB and write the scalar.
  __threadfence();
  __shared__ float rs[2], rc[2];
  float acc = 0.0f;
  for (int bb = 0; bb < B; ++bb) {
    float s = 0.0f, cc = 0.0f;
    for (int k = threadIdx.x; k < T; k += TPB) {
      union { float2 f; unsigned long long u; } pk;
      pk.u = __hip_atomic_load((const unsigned long long*)&part[bb * T + k],
                               __ATOMIC_RELAXED, __HIP_MEMORY_SCOPE_AGENT);
      s += pk.f.x;
      cc += pk.f.y;
    }
    for (int off = 32; off > 0; off >>= 1) {
      s += __shfl_down(s, off, 64);
      cc += __shfl_down(cc, off, 64);
    }
    if (lane == 0) { rs[wv] = s; rc[wv] = cc; }
    __syncthreads();
    if (threadIdx.x == 0) acc += (rs[0] + rs[1]) / fmaxf(rc[0] + rc[1], 1.0f);
    __syncthreads();
  }
  if (threadIdx.x == 0) out[0] = 1.0f - acc / (float)B;
}

extern "C" void kernel_launch(void* const* d_in, const int* in_sizes, int n_in,
                              void* d_out, int out_size, void* d_ws, size_t ws_size,
                              hipStream_t stream)
{
  const float* pred  = (const float*)d_in[0];
  const float* truec = (const float*)d_in[1];
  const int*   isdna = (const int*)d_in[2];
  const int*   isrna = (const int*)d_in[3];
  float* out = (float*)d_out;
  float2* part = (float2*)d_ws;        // 4160 * 8B partials, rewritten each iter

  const int B = 2;
  const int N = in_sizes[2] / B;       // 4096
  const int C = N / 64;                // 64 chunks
  const int T = C * (C + 1) / 2;       // 2080 triangle tiles; T*B = 64*65

  dim3 grid(T, B);                     // 1 tile per block, K split across 2 waves
  lddt_fused<<<grid, TPB, 0, stream>>>(pred, truec, isdna, isrna, part, out, N, C);
}

// Round 4
// 75.687 us; speedup vs baseline: 2.3426x; 1.7513x over previous
//
#include <hip/hip_runtime.h>
#include <math.h>

#define TPB 128   // 2 waves per block; both waves share one 64x64 tile, split on K

// Coords pre-scaled by log2(e): exp2(|dt'-dp'|) == e^{|dt-dp|}; cutoff test
// runs on squared scaled distances (no sqrt->cmp dependency).
#define L2E 1.4426950408889634f

// sum_k sigmoid(a_k - d) = num(e)/den(e), e = exp(d), a_k = .5,1,2,4.
// Coefficients: elementary symmetric functions of C_k = e^{-a_k}.
#define A1c 1.1280610230094226f
#define A2c 0.3753279228541867f
#define A3c 0.0366994760193147f
#define A4c 0.0005530843701478f
#define B1c 3.3841830690282678f   // 3*A1
#define B2c 0.7506558457083734f   // 2*A2
#define B3c 0.0366994760193147f   // A3
// Self-pair (d=0, e=1): eps = sig(.5)+sig(1)+sig(2)+sig(4) = 3.2163290...
#define EPS_SELF 3.2163290f

typedef float f2 __attribute__((ext_vector_type(2)));

static __device__ __forceinline__ f2 f2fma(f2 a, f2 b, f2 c) {
  return __builtin_elementwise_fma(a, b, c);
}
static __device__ __forceinline__ f2 splat(float x) {
  f2 r; r.x = x; r.y = x; return r;
}

__global__ __launch_bounds__(TPB, 6) void lddt_pairs(
    const float* __restrict__ pred, const float* __restrict__ truec,
    const int* __restrict__ isdna, const int* __restrict__ isrna,
    float2* __restrict__ part, int N, int C)
{
  const int wv   = threadIdx.x >> 6;   // which K-half of the tile (0/1)
  const int lane = threadIdx.x & 63;
  const int t = blockIdx.x;            // linear upper-triangle tile id
  const int b = blockIdx.y;

  // tile id -> (ic, jc), jc >= ic (wave-uniform scalar math)
  const float fC = (float)C;
  int ic = (int)((2.0f*fC + 1.0f -
                  sqrtf((2.0f*fC + 1.0f)*(2.0f*fC + 1.0f) - 8.0f*(float)t)) * 0.5f);
  if (ic > C - 1) ic = C - 1;
  if (ic < 0) ic = 0;
  while (ic > 0 && t < ic*C - ((ic*(ic-1)) >> 1)) --ic;
  while (t >= (ic+1)*C - (((ic+1)*ic) >> 1)) ++ic;
  const int jc = ic + t - (ic*C - ((ic*(ic-1)) >> 1));
  const bool diag = (ic == jc);

  const float C30SQ = (30.0f*L2E)*(30.0f*L2E);
  const float C15SQ = (15.0f*L2E)*(15.0f*L2E);

  // SoA j-tile staging: f2 element k packs j = 2k, 2k+1 (wave-uniform
  // broadcast ds_read_b64 in the loop -> conflict-free).
  __shared__ f2 spx[32], spy[32], spz[32];
  __shared__ f2 stx[32], sty[32], stz[32];
  __shared__ f2 scut[32];
  __shared__ float2 blkred[2];

  {
    const int j = jc * 64 + lane;
    const size_t jb = (size_t)b * N + j;
    if (wv == 0) {       // wave 0 stages pred coords + cutoff class
      const float* pp = pred + jb * 3;
      ((float*)spx)[lane] = pp[0]*L2E;
      ((float*)spy)[lane] = pp[1]*L2E;
      ((float*)spz)[lane] = pp[2]*L2E;
      ((float*)scut)[lane] = ((isdna[jb] | isrna[jb]) != 0) ? C30SQ : C15SQ;
    } else {             // wave 1 stages true coords
      const float* tt = truec + jb * 3;
      ((float*)stx)[lane] = tt[0]*L2E;
      ((float*)sty)[lane] = tt[1]*L2E;
      ((float*)stz)[lane] = tt[2]*L2E;
    }
  }

  const int i = ic * 64 + lane;
  const size_t ib = (size_t)b * N + i;
  const f2 pix2 = splat(pred[ib*3+0]*L2E);
  const f2 piy2 = splat(pred[ib*3+1]*L2E);
  const f2 piz2 = splat(pred[ib*3+2]*L2E);
  const f2 tix2 = splat(truec[ib*3+0]*L2E);
  const f2 tiy2 = splat(truec[ib*3+1]*L2E);
  const f2 tiz2 = splat(truec[ib*3+2]*L2E);
  // cutoff = (nuc_i && nuc_j) ? 30 : 15  ==  min(cut_i, cut_j)
  const f2 cuti2 = splat(((isdna[ib] | isrna[ib]) != 0) ? C30SQ : C15SQ);

  const f2 vA4 = splat(A4c), vA3 = splat(A3c), vA2 = splat(A2c), vA1 = splat(A1c);
  const f2 vB3 = splat(B3c), vB2 = splat(B2c), vB1 = splat(B1c);
  const f2 v1 = splat(1.0f), v4 = splat(4.0f);

  __syncthreads();

  f2  sum2 = splat(0.0f);
  int cnt = 0;

  // Branch-free packed loop over this wave's K-half; diag tiles include the
  // self-pair (d=0 -> e=1, eps=EPS_SELF, inc=true exactly) subtracted
  // analytically after the loop.
  const int k0 = wv * 16;
#pragma unroll 4
  for (int k = k0; k < k0 + 16; ++k) {
    f2 dx = spx[k] - pix2;
    f2 dy = spy[k] - piy2;
    f2 dz = spz[k] - piz2;
    f2 d2p = f2fma(dx, dx, f2fma(dy, dy, dz * dz));
    f2 ex = stx[k] - tix2;
    f2 ey = sty[k] - tiy2;
    f2 ez = stz[k] - tiz2;
    f2 d2t = f2fma(ex, ex, f2fma(ey, ey, ez * ez));

    f2 dpv, dtv;
    dpv.x = __builtin_amdgcn_sqrtf(d2p.x);
    dpv.y = __builtin_amdgcn_sqrtf(d2p.y);
    dtv.x = __builtin_amdgcn_sqrtf(d2t.x);
    dtv.y = __builtin_amdgcn_sqrtf(d2t.y);
    f2 diff = dtv - dpv;

    f2 e;
    e.x = __builtin_amdgcn_exp2f(fabsf(diff.x));
    e.y = __builtin_amdgcn_exp2f(fabsf(diff.y));

    f2 den = f2fma(f2fma(f2fma(f2fma(vA4, e, vA3), e, vA2), e, vA1), e, v1);
    f2 num = f2fma(f2fma(f2fma(vB3, e, vB2), e, vB1), e, v4);
    f2 r;
    r.x = __builtin_amdgcn_rcpf(den.x);
    r.y = __builtin_amdgcn_rcpf(den.y);
    f2 eps = num * r;

    f2 cut = __builtin_elementwise_min(cuti2, scut[k]);
    bool i0 = d2t.x < cut.x;
    bool i1 = d2t.y < cut.y;
    cnt += (int)__popcll(__ballot(i0));
    cnt += (int)__popcll(__ballot(i1));
    f2 add;
    add.x = i0 ? eps.x : 0.0f;
    add.y = i1 ? eps.y : 0.0f;
    sum2 += add;
  }

  float sum = sum2.x + sum2.y;
  // Self-pairs of a diag tile: lane L's self is at k = L>>1, which lives in
  // wave (L>>5)'s K-half; each wave's ballots counted 32 of them.
  if (diag) {
    if ((lane >> 5) == wv) sum -= EPS_SELF;
    cnt -= 32;
  }

  // wave64 butterfly reduce on sum (cnt already wave-uniform via ballot)
  for (int off = 32; off > 0; off >>= 1)
    sum += __shfl_down(sum, off, 64);

  if (lane == 0) {
    const float w = diag ? 1.0f : 2.0f;
    blkred[wv] = make_float2(0.25f * w * sum, w * (float)cnt);
  }
  __syncthreads();
  if (threadIdx.x == 0) {
    const float2 a = blkred[0], c = blkred[1];
    part[(size_t)b * gridDim.x + blockIdx.x] = make_float2(a.x + c.x, a.y + c.y);
  }
}

__global__ __launch_bounds__(1024) void lddt_final(
    const float2* __restrict__ part, float* __restrict__ out, int B, int P)
{
  __shared__ float rs[16], rc[16];
  float acc = 0.0f;
  for (int b = 0; b < B; ++b) {
    float s = 0.0f, c = 0.0f;
    for (int k = threadIdx.x; k < P; k += 1024) {
      const float2 p = part[(size_t)b * P + k];
      s += p.x;
      c += p.y;
    }
    for (int off = 32; off > 0; off >>= 1) {
      s += __shfl_down(s, off, 64);
      c += __shfl_down(c, off, 64);
    }
    const int wave = threadIdx.x >> 6, lane = threadIdx.x & 63;
    if (lane == 0) { rs[wave] = s; rc[wave] = c; }
    __syncthreads();
    if (threadIdx.x == 0) {
      float S = 0.0f, Cc = 0.0f;
      for (int w = 0; w < 16; ++w) { S += rs[w]; Cc += rc[w]; }
      acc += S / fmaxf(Cc, 1.0f);
    }
    __syncthreads();
  }
  if (threadIdx.x == 0) out[0] = 1.0f - acc / (float)B;
}

extern "C" void kernel_launch(void* const* d_in, const int* in_sizes, int n_in,
                              void* d_out, int out_size, void* d_ws, size_t ws_size,
                              hipStream_t stream)
{
  const float* pred  = (const float*)d_in[0];
  const float* truec = (const float*)d_in[1];
  const int*   isdna = (const int*)d_in[2];
  const int*   isrna = (const int*)d_in[3];
  float* out = (float*)d_out;
  float2* part = (float2*)d_ws;

  const int B = 2;
  const int N = in_sizes[2] / B;       // 4096
  const int C = N / 64;                // 64 chunks
  const int T = C * (C + 1) / 2;       // 2080 triangle tiles

  dim3 grid(T, B);                     // 1 tile per block, K split across 2 waves
  lddt_pairs<<<grid, TPB, 0, stream>>>(pred, truec, isdna, isrna, part, N, C);
  lddt_final<<<1, 1024, 0, stream>>>(part, out, B, T);
}